// Round 1
// baseline (704.912 us; speedup 1.0000x reference)
//
#include <hip/hip_runtime.h>
#include <hip/hip_bf16.h>

typedef __bf16 bf16x4 __attribute__((ext_vector_type(4)));
typedef __bf16 bf16x8 __attribute__((ext_vector_type(8)));
typedef float  floatx4 __attribute__((ext_vector_type(4)));

#define BM 128
#define BN 128
#define BK 32

// 128x128 C-tile per block, 256 threads = 4 waves, each wave 64x64 via 4x4
// grid of v_mfma_f32_16x16x32_bf16. Inputs fp32/int32 are converted to bf16
// in registers during staging (wq in [-8,7] is exact in bf16; scale/bias
// folded in fp32 epilogue -> only x's bf16 rounding contributes error).
__global__ __launch_bounds__(256)
void fp4linear_gemm(const float* __restrict__ X, const int* __restrict__ W,
                    const float* __restrict__ scale, const float* __restrict__ bias,
                    float* __restrict__ Out, int M, int N, int K)
{
    __shared__ __bf16 sA[BM * BK];   // 8 KB, row-major [m][k], unpadded
    __shared__ __bf16 sB[BN * BK];   // 8 KB, row-major [n][k], unpadded

    const int tid  = threadIdx.x;
    const int row0 = blockIdx.y * BM;
    const int col0 = blockIdx.x * BN;

    const int wave = tid >> 6;
    const int lane = tid & 63;
    const int wm = (wave >> 1) * 64;   // wave row offset in tile
    const int wn = (wave & 1) * 64;    // wave col offset in tile
    const int lm = lane & 15;
    const int kq = lane >> 4;          // 0..3, k-quad

    floatx4 acc[4][4];
#pragma unroll
    for (int i = 0; i < 4; ++i)
#pragma unroll
        for (int j = 0; j < 4; ++j)
            acc[i][j] = (floatx4)0.0f;

    for (int k0 = 0; k0 < K; k0 += BK) {
        // ---- issue global loads before the barrier (overlap with prior compute)
        float4 fa[4];
        int4   ib[4];
#pragma unroll
        for (int l = 0; l < 4; ++l) {
            int idx = tid + l * 256;          // 0..1023
            int r   = idx >> 3;               // row 0..127
            int c4  = idx & 7;                // float4 column
            fa[l] = *reinterpret_cast<const float4*>(
                        &X[(size_t)(row0 + r) * K + k0 + c4 * 4]);
        }
#pragma unroll
        for (int l = 0; l < 4; ++l) {
            int idx = tid + l * 256;
            int r   = idx >> 3;
            int c4  = idx & 7;
            ib[l] = *reinterpret_cast<const int4*>(
                        &W[(size_t)(col0 + r) * K + k0 + c4 * 4]);
        }

        __syncthreads();   // prior iteration's LDS reads done before overwrite

        // ---- convert + store to LDS (bf16x4 = 8B ds_write_b64)
#pragma unroll
        for (int l = 0; l < 4; ++l) {
            int idx = tid + l * 256;
            int r   = idx >> 3;
            int c4  = idx & 7;
            bf16x4 h;
            h[0] = (__bf16)fa[l].x; h[1] = (__bf16)fa[l].y;
            h[2] = (__bf16)fa[l].z; h[3] = (__bf16)fa[l].w;
            *reinterpret_cast<bf16x4*>(&sA[r * BK + c4 * 4]) = h;
        }
#pragma unroll
        for (int l = 0; l < 4; ++l) {
            int idx = tid + l * 256;
            int r   = idx >> 3;
            int c4  = idx & 7;
            bf16x4 h;
            h[0] = (__bf16)(float)ib[l].x; h[1] = (__bf16)(float)ib[l].y;
            h[2] = (__bf16)(float)ib[l].z; h[3] = (__bf16)(float)ib[l].w;
            *reinterpret_cast<bf16x4*>(&sB[r * BK + c4 * 4]) = h;
        }

        __syncthreads();

        // ---- LDS -> fragments (ds_read_b128) and 16 MFMAs
        bf16x8 af[4], bfr[4];
#pragma unroll
        for (int i = 0; i < 4; ++i)
            af[i] = *reinterpret_cast<const bf16x8*>(
                        &sA[(wm + i * 16 + lm) * BK + kq * 8]);
#pragma unroll
        for (int j = 0; j < 4; ++j)
            bfr[j] = *reinterpret_cast<const bf16x8*>(
                        &sB[(wn + j * 16 + lm) * BK + kq * 8]);
#pragma unroll
        for (int i = 0; i < 4; ++i)
#pragma unroll
            for (int j = 0; j < 4; ++j)
                acc[i][j] = __builtin_amdgcn_mfma_f32_16x16x32_bf16(
                                af[i], bfr[j], acc[i][j], 0, 0, 0);
    }

    // ---- epilogue: C/D layout col=lane&15, row=(lane>>4)*4+reg (m89-verified)
#pragma unroll
    for (int j = 0; j < 4; ++j) {
        int n = col0 + wn + j * 16 + lm;
        float sc = scale[n];
        float bi = bias[n];
#pragma unroll
        for (int i = 0; i < 4; ++i) {
#pragma unroll
            for (int r = 0; r < 4; ++r) {
                int m = row0 + wm + i * 16 + kq * 4 + r;
                Out[(size_t)m * N + n] = sc * acc[i][j][r] + bi;
            }
        }
    }
}

extern "C" void kernel_launch(void* const* d_in, const int* in_sizes, int n_in,
                              void* d_out, int out_size, void* d_ws, size_t ws_size,
                              hipStream_t stream) {
    const float* x     = (const float*)d_in[0];
    const int*   wq    = (const int*)d_in[1];
    const float* scale = (const float*)d_in[2];
    const float* bias  = (const float*)d_in[3];
    float* out = (float*)d_out;

    const int N = in_sizes[2];            // OUT = 4096
    const int K = in_sizes[1] / N;        // IN  = 4096
    const int M = in_sizes[0] / K;        // B*S = 8192

    dim3 grid(N / BN, M / BM);            // (32, 64)
    dim3 block(256);
    hipLaunchKernelGGL(fp4linear_gemm, grid, block, 0, stream,
                       x, wq, scale, bias, out, M, N, K);
}

// Round 2
// 666.037 us; speedup vs baseline: 1.0584x; 1.0584x over previous
//
#include <hip/hip_runtime.h>
#include <hip/hip_bf16.h>

typedef __bf16 bf16x4 __attribute__((ext_vector_type(4)));
typedef __bf16 bf16x8 __attribute__((ext_vector_type(8)));
typedef float  floatx4 __attribute__((ext_vector_type(4)));

#define BM 128
#define BN 128
#define BK 32

#define AS1 __attribute__((address_space(1)))
#define AS3 __attribute__((address_space(3)))

// ---------------------------------------------------------------------------
// Prepass: fp32 -> bf16 (x) and int32 -> bf16 (wq). Memory-bound, ~50us.
// ---------------------------------------------------------------------------
__global__ __launch_bounds__(256)
void cvt_f32_bf16(const float* __restrict__ in, __bf16* __restrict__ out, int n8)
{
    int i = blockIdx.x * 256 + threadIdx.x;
    if (i >= n8) return;
    const float4* p = reinterpret_cast<const float4*>(in) + i * 2;
    float4 a = p[0], b = p[1];
    bf16x8 h;
    h[0] = (__bf16)a.x; h[1] = (__bf16)a.y; h[2] = (__bf16)a.z; h[3] = (__bf16)a.w;
    h[4] = (__bf16)b.x; h[5] = (__bf16)b.y; h[6] = (__bf16)b.z; h[7] = (__bf16)b.w;
    reinterpret_cast<bf16x8*>(out)[i] = h;
}

__global__ __launch_bounds__(256)
void cvt_i32_bf16(const int* __restrict__ in, __bf16* __restrict__ out, int n8)
{
    int i = blockIdx.x * 256 + threadIdx.x;
    if (i >= n8) return;
    const int4* p = reinterpret_cast<const int4*>(in) + i * 2;
    int4 a = p[0], b = p[1];
    bf16x8 h;
    h[0] = (__bf16)(float)a.x; h[1] = (__bf16)(float)a.y;
    h[2] = (__bf16)(float)a.z; h[3] = (__bf16)(float)a.w;
    h[4] = (__bf16)(float)b.x; h[5] = (__bf16)(float)b.y;
    h[6] = (__bf16)(float)b.z; h[7] = (__bf16)(float)b.w;
    reinterpret_cast<bf16x8*>(out)[i] = h;
}

// ---------------------------------------------------------------------------
// m97-style GEMM: 128x128 tile, BK=32, global_load_lds width=16, 2-barrier
// K-loop, 4 waves x (4x4 grid of mfma_f32_16x16x32_bf16).
// Both A (x) and B (w) are K-contiguous bf16 ("B^T" gemm_bt layout).
// ---------------------------------------------------------------------------
__global__ __launch_bounds__(256)
void gemm_bf16_bt(const __bf16* __restrict__ A, const __bf16* __restrict__ B,
                  const float* __restrict__ scale, const float* __restrict__ bias,
                  float* __restrict__ Out, int M, int N, int K)
{
    __shared__ __bf16 sA[BM * BK];   // 8 KB row-major [m][k], 64B rows
    __shared__ __bf16 sB[BN * BK];   // 8 KB row-major [n][k]

    const int tid  = threadIdx.x;
    const int row0 = blockIdx.y * BM;
    const int col0 = blockIdx.x * BN;
    const int wave = tid >> 6;
    const int lane = tid & 63;

    // --- staging geometry: each wave DMAs 1024B (16 rows x 64B) per call.
    // LDS dest = wave-uniform base + lane*16 (HW rule, m104/m108).
    // lane l -> tile row (l>>2), halfword col (l&3)*8 within its 16-row chunk.
    const int sRow = lane >> 2;
    const int sCol = (lane & 3) * 8;
    const size_t aOff0 = (size_t)(row0 + wave * 16 + sRow) * K + sCol;       // chunk 0
    const size_t aOff1 = aOff0 + (size_t)64 * K;                             // chunk 1
    const size_t bOff0 = (size_t)(col0 + wave * 16 + sRow) * K + sCol;
    const size_t bOff1 = bOff0 + (size_t)64 * K;
    AS3 __bf16* ldsA0 = (AS3 __bf16*)&sA[wave * 512];          // bytes: wave*1024
    AS3 __bf16* ldsA1 = (AS3 __bf16*)&sA[2048 + wave * 512];
    AS3 __bf16* ldsB0 = (AS3 __bf16*)&sB[wave * 512];
    AS3 __bf16* ldsB1 = (AS3 __bf16*)&sB[2048 + wave * 512];

    // --- fragment geometry
    const int wm = (wave >> 1) * 64;
    const int wn = (wave & 1) * 64;
    const int lm = lane & 15;
    const int kq = lane >> 4;

    floatx4 acc[4][4];
#pragma unroll
    for (int i = 0; i < 4; ++i)
#pragma unroll
        for (int j = 0; j < 4; ++j)
            acc[i][j] = (floatx4)0.0f;

    for (int k0 = 0; k0 < K; k0 += BK) {
        __builtin_amdgcn_global_load_lds((const AS1 void*)(A + aOff0 + k0),
                                         (AS3 void*)ldsA0, 16, 0, 0);
        __builtin_amdgcn_global_load_lds((const AS1 void*)(A + aOff1 + k0),
                                         (AS3 void*)ldsA1, 16, 0, 0);
        __builtin_amdgcn_global_load_lds((const AS1 void*)(B + bOff0 + k0),
                                         (AS3 void*)ldsB0, 16, 0, 0);
        __builtin_amdgcn_global_load_lds((const AS1 void*)(B + bOff1 + k0),
                                         (AS3 void*)ldsB1, 16, 0, 0);
        __syncthreads();   // drains vmcnt: DMA'd tile visible to all waves

        bf16x8 af[4], bfr[4];
#pragma unroll
        for (int i = 0; i < 4; ++i)
            af[i] = *reinterpret_cast<const bf16x8*>(
                        &sA[(wm + i * 16 + lm) * BK + kq * 8]);
#pragma unroll
        for (int j = 0; j < 4; ++j)
            bfr[j] = *reinterpret_cast<const bf16x8*>(
                        &sB[(wn + j * 16 + lm) * BK + kq * 8]);
#pragma unroll
        for (int i = 0; i < 4; ++i)
#pragma unroll
            for (int j = 0; j < 4; ++j)
                acc[i][j] = __builtin_amdgcn_mfma_f32_16x16x32_bf16(
                                af[i], bfr[j], acc[i][j], 0, 0, 0);
        __syncthreads();   // all waves done reading before next DMA overwrite
    }

    // --- epilogue: C/D layout col=lane&15, row=(lane>>4)*4+reg (m89-verified)
#pragma unroll
    for (int j = 0; j < 4; ++j) {
        int n = col0 + wn + j * 16 + lm;
        float sc = scale[n];
        float bi = bias[n];
#pragma unroll
        for (int i = 0; i < 4; ++i) {
#pragma unroll
            for (int r = 0; r < 4; ++r) {
                int m = row0 + wm + i * 16 + kq * 4 + r;
                Out[(size_t)m * N + n] = sc * acc[i][j][r] + bi;
            }
        }
    }
}

// ---------------------------------------------------------------------------
// Fallback (round-1 kernel): fused conversion in staging, no workspace needed.
// ---------------------------------------------------------------------------
__global__ __launch_bounds__(256)
void fp4linear_gemm(const float* __restrict__ X, const int* __restrict__ W,
                    const float* __restrict__ scale, const float* __restrict__ bias,
                    float* __restrict__ Out, int M, int N, int K)
{
    __shared__ __bf16 sA[BM * BK];
    __shared__ __bf16 sB[BN * BK];

    const int tid  = threadIdx.x;
    const int row0 = blockIdx.y * BM;
    const int col0 = blockIdx.x * BN;
    const int wave = tid >> 6;
    const int lane = tid & 63;
    const int wm = (wave >> 1) * 64;
    const int wn = (wave & 1) * 64;
    const int lm = lane & 15;
    const int kq = lane >> 4;

    floatx4 acc[4][4];
#pragma unroll
    for (int i = 0; i < 4; ++i)
#pragma unroll
        for (int j = 0; j < 4; ++j)
            acc[i][j] = (floatx4)0.0f;

    for (int k0 = 0; k0 < K; k0 += BK) {
        float4 fa[4];
        int4   ib[4];
#pragma unroll
        for (int l = 0; l < 4; ++l) {
            int idx = tid + l * 256;
            int r = idx >> 3, c4 = idx & 7;
            fa[l] = *reinterpret_cast<const float4*>(
                        &X[(size_t)(row0 + r) * K + k0 + c4 * 4]);
        }
#pragma unroll
        for (int l = 0; l < 4; ++l) {
            int idx = tid + l * 256;
            int r = idx >> 3, c4 = idx & 7;
            ib[l] = *reinterpret_cast<const int4*>(
                        &W[(size_t)(col0 + r) * K + k0 + c4 * 4]);
        }
        __syncthreads();
#pragma unroll
        for (int l = 0; l < 4; ++l) {
            int idx = tid + l * 256;
            int r = idx >> 3, c4 = idx & 7;
            bf16x4 h;
            h[0] = (__bf16)fa[l].x; h[1] = (__bf16)fa[l].y;
            h[2] = (__bf16)fa[l].z; h[3] = (__bf16)fa[l].w;
            *reinterpret_cast<bf16x4*>(&sA[r * BK + c4 * 4]) = h;
        }
#pragma unroll
        for (int l = 0; l < 4; ++l) {
            int idx = tid + l * 256;
            int r = idx >> 3, c4 = idx & 7;
            bf16x4 h;
            h[0] = (__bf16)(float)ib[l].x; h[1] = (__bf16)(float)ib[l].y;
            h[2] = (__bf16)(float)ib[l].z; h[3] = (__bf16)(float)ib[l].w;
            *reinterpret_cast<bf16x4*>(&sB[r * BK + c4 * 4]) = h;
        }
        __syncthreads();

        bf16x8 af[4], bfr[4];
#pragma unroll
        for (int i = 0; i < 4; ++i)
            af[i] = *reinterpret_cast<const bf16x8*>(
                        &sA[(wm + i * 16 + lm) * BK + kq * 8]);
#pragma unroll
        for (int j = 0; j < 4; ++j)
            bfr[j] = *reinterpret_cast<const bf16x8*>(
                        &sB[(wn + j * 16 + lm) * BK + kq * 8]);
#pragma unroll
        for (int i = 0; i < 4; ++i)
#pragma unroll
            for (int j = 0; j < 4; ++j)
                acc[i][j] = __builtin_amdgcn_mfma_f32_16x16x32_bf16(
                                af[i], bfr[j], acc[i][j], 0, 0, 0);
    }

#pragma unroll
    for (int j = 0; j < 4; ++j) {
        int n = col0 + wn + j * 16 + lm;
        float sc = scale[n];
        float bi = bias[n];
#pragma unroll
        for (int i = 0; i < 4; ++i) {
#pragma unroll
            for (int r = 0; r < 4; ++r) {
                int m = row0 + wm + i * 16 + kq * 4 + r;
                Out[(size_t)m * N + n] = sc * acc[i][j][r] + bi;
            }
        }
    }
}

extern "C" void kernel_launch(void* const* d_in, const int* in_sizes, int n_in,
                              void* d_out, int out_size, void* d_ws, size_t ws_size,
                              hipStream_t stream) {
    const float* x     = (const float*)d_in[0];
    const int*   wq    = (const int*)d_in[1];
    const float* scale = (const float*)d_in[2];
    const float* bias  = (const float*)d_in[3];
    float* out = (float*)d_out;

    const int N = in_sizes[2];            // OUT = 4096
    const int K = in_sizes[1] / N;        // IN  = 4096
    const int M = in_sizes[0] / K;        // B*S = 8192

    const size_t xElems = (size_t)M * K;
    const size_t wElems = (size_t)N * K;
    const size_t need   = (xElems + wElems) * sizeof(__bf16);

    dim3 grid(N / BN, M / BM);
    dim3 block(256);

    if (ws_size >= need && (xElems % 8 == 0) && (wElems % 8 == 0)) {
        __bf16* xb = (__bf16*)d_ws;
        __bf16* wb = xb + xElems;
        int nx8 = (int)(xElems / 8);
        int nw8 = (int)(wElems / 8);
        hipLaunchKernelGGL(cvt_f32_bf16, dim3((nx8 + 255) / 256), block, 0, stream,
                           x, xb, nx8);
        hipLaunchKernelGGL(cvt_i32_bf16, dim3((nw8 + 255) / 256), block, 0, stream,
                           wq, wb, nw8);
        hipLaunchKernelGGL(gemm_bf16_bt, grid, block, 0, stream,
                           xb, wb, scale, bias, out, M, N, K);
    } else {
        hipLaunchKernelGGL(fp4linear_gemm, grid, block, 0, stream,
                           x, wq, scale, bias, out, M, N, K);
    }
}

// Round 3
// 596.256 us; speedup vs baseline: 1.1822x; 1.1170x over previous
//
#include <hip/hip_runtime.h>
#include <hip/hip_bf16.h>

typedef __bf16 bf16x4 __attribute__((ext_vector_type(4)));
typedef __bf16 bf16x8 __attribute__((ext_vector_type(8)));
typedef float  floatx4 __attribute__((ext_vector_type(4)));

#define BM 128
#define BN 128
#define BK 64

#define AS1 __attribute__((address_space(1)))
#define AS3 __attribute__((address_space(3)))

// ---------------------------------------------------------------------------
// Merged prepass: fp32->bf16 (x) and int32->bf16 (wq), one launch.
// ---------------------------------------------------------------------------
__global__ __launch_bounds__(256)
void cvt_both(const float* __restrict__ xin, const int* __restrict__ win,
              __bf16* __restrict__ xout, __bf16* __restrict__ wout,
              int nx8, int nw8)
{
    int i = blockIdx.x * 256 + threadIdx.x;
    if (i < nx8) {
        const float4* p = reinterpret_cast<const float4*>(xin) + (size_t)i * 2;
        float4 a = p[0], b = p[1];
        bf16x8 h;
        h[0] = (__bf16)a.x; h[1] = (__bf16)a.y; h[2] = (__bf16)a.z; h[3] = (__bf16)a.w;
        h[4] = (__bf16)b.x; h[5] = (__bf16)b.y; h[6] = (__bf16)b.z; h[7] = (__bf16)b.w;
        reinterpret_cast<bf16x8*>(xout)[i] = h;
    } else {
        int j = i - nx8;
        if (j < nw8) {
            const int4* p = reinterpret_cast<const int4*>(win) + (size_t)j * 2;
            int4 a = p[0], b = p[1];
            bf16x8 h;
            h[0] = (__bf16)(float)a.x; h[1] = (__bf16)(float)a.y;
            h[2] = (__bf16)(float)a.z; h[3] = (__bf16)(float)a.w;
            h[4] = (__bf16)(float)b.x; h[5] = (__bf16)(float)b.y;
            h[6] = (__bf16)(float)b.z; h[7] = (__bf16)(float)b.w;
            reinterpret_cast<bf16x8*>(wout)[j] = h;
        }
    }
}

// ---------------------------------------------------------------------------
// GEMM v3: 128x128 tile, BK=64, global_load_lds width=16, XOR-swizzled LDS.
// LDS row stride = 128 B (exact bank wrap) so bank = colblock only; storing
// global (row, blk^(row&7)) at LDS (row, blk) makes each k-quad's 16 lanes
// hit 8 bank-groups 2-way (free, m136). 32 MFMA per barrier pair (64 iters).
// ---------------------------------------------------------------------------
__global__ __launch_bounds__(256)
void gemm_bf16_bt(const __bf16* __restrict__ A, const __bf16* __restrict__ B,
                  const float* __restrict__ scale, const float* __restrict__ bias,
                  float* __restrict__ Out, int M, int N, int K)
{
    __shared__ __bf16 sA[BM * BK];   // 16 KB, [m][k64], row = 128 B
    __shared__ __bf16 sB[BN * BK];   // 16 KB, [n][k64]

    const int tid  = threadIdx.x;
    const int row0 = blockIdx.y * BM;
    const int col0 = blockIdx.x * BN;
    const int wave = tid >> 6;
    const int lane = tid & 63;

    // --- DMA geometry: one call = 8 rows x 128 B = 1024 B per wave.
    // lane l -> row (l>>3), stored blk (l&7); fetch global blk = (l&7)^(l>>3).
    const int sRow = lane >> 3;            // 0..7 within 8-row chunk
    const int gBlk = (lane & 7) ^ sRow;    // swizzled 16B-block in the row
    // wave w owns rows [w*32, w*32+32), 4 calls of 8 rows each.
    size_t aOff[4], bOff[4];
    const __bf16* ldsA[4];
    const __bf16* ldsB[4];
#pragma unroll
    for (int q = 0; q < 4; ++q) {
        int r = wave * 32 + q * 8 + sRow;
        aOff[q] = (size_t)(row0 + r) * K + gBlk * 8;
        bOff[q] = (size_t)(col0 + r) * K + gBlk * 8;
        ldsA[q] = &sA[(wave * 32 + q * 8) * BK];
        ldsB[q] = &sB[(wave * 32 + q * 8) * BK];
    }

    // --- fragment geometry
    const int wm = (wave >> 1) * 64;
    const int wn = (wave & 1) * 64;
    const int lm = lane & 15;
    const int kq = lane >> 4;
    const int sw = lm & 7;                 // row-derived XOR for frag reads

    floatx4 acc[4][4];
#pragma unroll
    for (int i = 0; i < 4; ++i)
#pragma unroll
        for (int j = 0; j < 4; ++j)
            acc[i][j] = (floatx4)0.0f;

    for (int k0 = 0; k0 < K; k0 += BK) {
#pragma unroll
        for (int q = 0; q < 4; ++q) {
            __builtin_amdgcn_global_load_lds((const AS1 void*)(A + aOff[q] + k0),
                                             (AS3 void*)ldsA[q], 16, 0, 0);
            __builtin_amdgcn_global_load_lds((const AS1 void*)(B + bOff[q] + k0),
                                             (AS3 void*)ldsB[q], 16, 0, 0);
        }
        __syncthreads();   // drains vmcnt: tile visible to all waves

#pragma unroll
        for (int h = 0; h < 2; ++h) {      // two k-halves of the BK=64 tile
            const int blkA = (kq + h * 4);
            bf16x8 af[4], bfr[4];
#pragma unroll
            for (int i = 0; i < 4; ++i) {
                int row = wm + i * 16 + lm;
                af[i] = *reinterpret_cast<const bf16x8*>(
                            &sA[row * BK + (blkA ^ sw) * 8]);
            }
#pragma unroll
            for (int j = 0; j < 4; ++j) {
                int row = wn + j * 16 + lm;
                bfr[j] = *reinterpret_cast<const bf16x8*>(
                            &sB[row * BK + (blkA ^ sw) * 8]);
            }
#pragma unroll
            for (int i = 0; i < 4; ++i)
#pragma unroll
                for (int j = 0; j < 4; ++j)
                    acc[i][j] = __builtin_amdgcn_mfma_f32_16x16x32_bf16(
                                    af[i], bfr[j], acc[i][j], 0, 0, 0);
        }
        __syncthreads();   // all waves done reading before next DMA overwrite
    }

    // --- epilogue: C/D layout col=lane&15, row=(lane>>4)*4+reg (m89-verified)
#pragma unroll
    for (int j = 0; j < 4; ++j) {
        int n = col0 + wn + j * 16 + lm;
        float sc = scale[n];
        float bi = bias[n];
#pragma unroll
        for (int i = 0; i < 4; ++i) {
#pragma unroll
            for (int r = 0; r < 4; ++r) {
                int m = row0 + wm + i * 16 + kq * 4 + r;
                Out[(size_t)m * N + n] = sc * acc[i][j][r] + bi;
            }
        }
    }
}

// ---------------------------------------------------------------------------
// Fallback (round-1 kernel): fused conversion in staging, no workspace needed.
// ---------------------------------------------------------------------------
__global__ __launch_bounds__(256)
void fp4linear_gemm(const float* __restrict__ X, const int* __restrict__ W,
                    const float* __restrict__ scale, const float* __restrict__ bias,
                    float* __restrict__ Out, int M, int N, int K)
{
    __shared__ __bf16 sA[BM * 32];
    __shared__ __bf16 sB[BN * 32];

    const int tid  = threadIdx.x;
    const int row0 = blockIdx.y * BM;
    const int col0 = blockIdx.x * BN;
    const int wave = tid >> 6;
    const int lane = tid & 63;
    const int wm = (wave >> 1) * 64;
    const int wn = (wave & 1) * 64;
    const int lm = lane & 15;
    const int kq = lane >> 4;

    floatx4 acc[4][4];
#pragma unroll
    for (int i = 0; i < 4; ++i)
#pragma unroll
        for (int j = 0; j < 4; ++j)
            acc[i][j] = (floatx4)0.0f;

    for (int k0 = 0; k0 < K; k0 += 32) {
        float4 fa[4];
        int4   ib[4];
#pragma unroll
        for (int l = 0; l < 4; ++l) {
            int idx = tid + l * 256;
            int r = idx >> 3, c4 = idx & 7;
            fa[l] = *reinterpret_cast<const float4*>(
                        &X[(size_t)(row0 + r) * K + k0 + c4 * 4]);
        }
#pragma unroll
        for (int l = 0; l < 4; ++l) {
            int idx = tid + l * 256;
            int r = idx >> 3, c4 = idx & 7;
            ib[l] = *reinterpret_cast<const int4*>(
                        &W[(size_t)(col0 + r) * K + k0 + c4 * 4]);
        }
        __syncthreads();
#pragma unroll
        for (int l = 0; l < 4; ++l) {
            int idx = tid + l * 256;
            int r = idx >> 3, c4 = idx & 7;
            bf16x4 h;
            h[0] = (__bf16)fa[l].x; h[1] = (__bf16)fa[l].y;
            h[2] = (__bf16)fa[l].z; h[3] = (__bf16)fa[l].w;
            *reinterpret_cast<bf16x4*>(&sA[r * 32 + c4 * 4]) = h;
        }
#pragma unroll
        for (int l = 0; l < 4; ++l) {
            int idx = tid + l * 256;
            int r = idx >> 3, c4 = idx & 7;
            bf16x4 h;
            h[0] = (__bf16)(float)ib[l].x; h[1] = (__bf16)(float)ib[l].y;
            h[2] = (__bf16)(float)ib[l].z; h[3] = (__bf16)(float)ib[l].w;
            *reinterpret_cast<bf16x4*>(&sB[r * 32 + c4 * 4]) = h;
        }
        __syncthreads();

        bf16x8 af[4], bfr[4];
#pragma unroll
        for (int i = 0; i < 4; ++i)
            af[i] = *reinterpret_cast<const bf16x8*>(
                        &sA[(wm + i * 16 + lm) * 32 + kq * 8]);
#pragma unroll
        for (int j = 0; j < 4; ++j)
            bfr[j] = *reinterpret_cast<const bf16x8*>(
                        &sB[(wn + j * 16 + lm) * 32 + kq * 8]);
#pragma unroll
        for (int i = 0; i < 4; ++i)
#pragma unroll
            for (int j = 0; j < 4; ++j)
                acc[i][j] = __builtin_amdgcn_mfma_f32_16x16x32_bf16(
                                af[i], bfr[j], acc[i][j], 0, 0, 0);
    }

#pragma unroll
    for (int j = 0; j < 4; ++j) {
        int n = col0 + wn + j * 16 + lm;
        float sc = scale[n];
        float bi = bias[n];
#pragma unroll
        for (int i = 0; i < 4; ++i) {
#pragma unroll
            for (int r = 0; r < 4; ++r) {
                int m = row0 + wm + i * 16 + kq * 4 + r;
                Out[(size_t)m * N + n] = sc * acc[i][j][r] + bi;
            }
        }
    }
}

extern "C" void kernel_launch(void* const* d_in, const int* in_sizes, int n_in,
                              void* d_out, int out_size, void* d_ws, size_t ws_size,
                              hipStream_t stream) {
    const float* x     = (const float*)d_in[0];
    const int*   wq    = (const int*)d_in[1];
    const float* scale = (const float*)d_in[2];
    const float* bias  = (const float*)d_in[3];
    float* out = (float*)d_out;

    const int N = in_sizes[2];            // OUT = 4096
    const int K = in_sizes[1] / N;        // IN  = 4096
    const int M = in_sizes[0] / K;        // B*S = 8192

    const size_t xElems = (size_t)M * K;
    const size_t wElems = (size_t)N * K;
    const size_t need   = (xElems + wElems) * sizeof(__bf16);

    dim3 grid(N / BN, M / BM);
    dim3 block(256);

    if (ws_size >= need && (xElems % 8 == 0) && (wElems % 8 == 0) && (K % BK == 0)) {
        __bf16* xb = (__bf16*)d_ws;
        __bf16* wb = xb + xElems;
        int nx8 = (int)(xElems / 8);
        int nw8 = (int)(wElems / 8);
        int total = nx8 + nw8;
        hipLaunchKernelGGL(cvt_both, dim3((total + 255) / 256), block, 0, stream,
                           x, wq, xb, wb, nx8, nw8);
        hipLaunchKernelGGL(gemm_bf16_bt, grid, block, 0, stream,
                           xb, wb, scale, bias, out, M, N, K);
    } else {
        hipLaunchKernelGGL(fp4linear_gemm, grid, block, 0, stream,
                           x, wq, scale, bias, out, M, N, K);
    }
}